// Round 5
// baseline (783.619 us; speedup 1.0000x reference)
//
#include <hip/hip_runtime.h>
#include <hip/hip_bf16.h>
#include <math.h>

// Problem constants (match reference)
#define T_TOK 1024
#define HID   2048
#define NEXP  64
#define IDIM  1024
#define ISH   2048      // IS = I * N_SHARED
#define TOPK  8

typedef float  f32x4  __attribute__((ext_vector_type(4)));
typedef __bf16 bf16x8 __attribute__((ext_vector_type(8)));

#define BM  64
#define BN_ 64
#define BK  64

// Barrier that does NOT drain vmcnt (waits own DS ops only).
#define BARRIER_NODRAIN() asm volatile("s_waitcnt lgkmcnt(0)\n\ts_barrier" ::: "memory")

__device__ __forceinline__ bf16x8 cvt8(f32x4 a, f32x4 b) {
  bf16x8 v;
  v[0]=(__bf16)a[0]; v[1]=(__bf16)a[1]; v[2]=(__bf16)a[2]; v[3]=(__bf16)a[3];
  v[4]=(__bf16)b[0]; v[5]=(__bf16)b[1]; v[6]=(__bf16)b[2]; v[7]=(__bf16)b[3];
  return v;
}

// ---------------- init: zero expert counts ----------------
__global__ void init_kernel(int* counts) {
  if (threadIdx.x < NEXP) counts[threadIdx.x] = 0;
}

// ---------------- x (f32) -> x_bf16 ----------------
__global__ void xcast_kernel(const float* __restrict__ x, __bf16* __restrict__ xb) {
  long i = ((long)blockIdx.x * 256 + threadIdx.x) * 8;
  f32x4 a = *(const f32x4*)(x + i);
  f32x4 b = *(const f32x4*)(x + i + 4);
  *(bf16x8*)(xb + i) = cvt8(a, b);
}

// ---------------- router: logits + sigmoid + grouped top-k (f32) ----------------
__global__ __launch_bounds__(256)
void router_kernel(const float* __restrict__ x, const float* __restrict__ gw,
                   const float* __restrict__ eb,
                   int* __restrict__ ids, float* __restrict__ wts,
                   int* __restrict__ counts)
{
  __shared__ __align__(16) float xs[HID];
  __shared__ float red[256];
  __shared__ float sc[NEXP], sb[NEXP];
  const int t = blockIdx.x, tid = threadIdx.x;

  const f32x4* xsrc = (const f32x4*)(x + (long)t * HID);
  f32x4* xd = (f32x4*)xs;
  xd[tid]       = xsrc[tid];
  xd[tid + 256] = xsrc[tid + 256];
  __syncthreads();

  const int e = tid & 63, part = tid >> 6;
  const f32x4* wrow = (const f32x4*)(gw + (long)e * HID + part * 512);
  const f32x4* xrow = (const f32x4*)(xs + part * 512);
  float s = 0.f;
  #pragma unroll 4
  for (int j = 0; j < 128; ++j) {
    f32x4 wv = wrow[j], xv = xrow[j];
    s += wv[0]*xv[0] + wv[1]*xv[1] + wv[2]*xv[2] + wv[3]*xv[3];
  }
  red[tid] = s;
  __syncthreads();
  if (part == 0) {
    float logit = red[e] + red[e+64] + red[e+128] + red[e+192];
    float sig = 1.f / (1.f + expf(-logit));   // accurate exp: selection must match f32 ref
    sc[e] = sig; sb[e] = sig + eb[e];
  }
  __syncthreads();

  if (tid == 0) {
    float gsc[8];
    for (int g = 0; g < 8; ++g) {
      float m1 = -1e30f, m2 = -1e30f;
      for (int j = 0; j < 8; ++j) {
        float v = sb[g*8 + j];
        if (v > m1) { m2 = m1; m1 = v; } else if (v > m2) m2 = v;
      }
      gsc[g] = m1 + m2;
    }
    unsigned gmask = 0;
    for (int it = 0; it < 4; ++it) {
      int best = 0; float bv = -1e30f;
      for (int g = 0; g < 8; ++g)
        if (!((gmask >> g) & 1) && gsc[g] > bv) { bv = gsc[g]; best = g; }
      gmask |= 1u << best;
    }
    unsigned long long taken = 0;
    int id8[8]; float wsum = 0.f;
    for (int it = 0; it < 8; ++it) {
      int best = 0; float bv = -1e30f;
      for (int e2 = 0; e2 < 64; ++e2) {
        if (!((gmask >> (e2 >> 3)) & 1)) continue;
        if ((taken >> e2) & 1) continue;
        float v = sb[e2];
        if (v > bv) { bv = v; best = e2; }
      }
      taken |= 1ull << best;
      id8[it] = best; wsum += sc[best];
    }
    float inv = 2.5f / wsum;   // fold ROUTED_SCALE into weights
    for (int k = 0; k < 8; ++k) {
      ids[t*8 + k] = id8[k];
      wts[t*8 + k] = sc[id8[k]] * inv;
      atomicAdd(&counts[id8[k]], 1);
    }
  }
}

// ---------------- prefix scan + (expert, mt) pair worklist (BM=64 chunks) ----
__global__ void scan_kernel(const int* __restrict__ counts,
                            int* __restrict__ seg_off, int* __restrict__ cursors,
                            int* __restrict__ pair_e, int* __restrict__ pair_mt,
                            int* __restrict__ npairs) {
  if (threadIdx.x == 0) {
    int off = 0, np = 0;
    for (int e = 0; e < NEXP; ++e) {
      seg_off[e] = off; cursors[e] = off;
      int c = counts[e]; off += c;
      for (int m = 0; m * BM < c; ++m) { pair_e[np] = e; pair_mt[np] = m; ++np; }
    }
    npairs[0] = np;
  }
}

// ---------------- scatter (t, w) into per-expert segments ----------------
__global__ void scatter_kernel(const int* __restrict__ ids, const float* __restrict__ wts,
                               int* __restrict__ cursors,
                               int* __restrict__ tok_list, float* __restrict__ wgt_list,
                               int* __restrict__ pos_of) {
  int idx = blockIdx.x * 256 + threadIdx.x;
  if (idx >= T_TOK * TOPK) return;
  int t = idx >> 3;
  int e = ids[idx];
  int pos = atomicAdd(&cursors[e], 1);
  tok_list[pos] = t;
  wgt_list[pos] = wts[idx];
  pos_of[idx] = pos;
}

// ---------------- fused gate+up streaming GEMM -> h = w*silu(g)*u (bf16) -----
// B (both weight streams) per-wave global->reg->bf16, no LDS. A double-buffered
// swizzled LDS, 64-row tile. Wave w owns cols [w*16, w*16+16).
template<bool ROUTED>
__global__ __launch_bounds__(256, 3)
void gu_kernel(const __bf16* __restrict__ A, const float* __restrict__ Bg0,
               const float* __restrict__ Bu0, long strideBe, int ldB, int K,
               __bf16* __restrict__ Hout, int ldh,
               const int* __restrict__ pair_e, const int* __restrict__ pair_mt,
               const int* __restrict__ npairs,
               const int* __restrict__ seg_off, const int* __restrict__ seg_cnt,
               const int* __restrict__ tok_list, const float* __restrict__ wgt_list,
               int Mfull)
{
  const int tid  = threadIdx.x;
  const int lane = tid & 63;
  const int wv   = tid >> 6;

  int e, mt0, soff, cnt;
  if (ROUTED) {
    int p = blockIdx.y;
    if (p >= npairs[0]) return;
    e = pair_e[p]; mt0 = pair_mt[p]; soff = seg_off[e]; cnt = seg_cnt[e];
  } else {
    e = 0; mt0 = blockIdx.y; soff = 0; cnt = Mfull;
  }
  const int rem = cnt - mt0 * BM;
  if (rem <= 0) return;

  const long bcol = (long)(blockIdx.x * BN_ + wv * 16 + (lane & 15));
  const float* Bg = Bg0 + (long)e * strideBe + bcol * ldB + ((lane >> 4) * 8);
  const float* Bu = Bu0 + (long)e * strideBe + bcol * ldB + ((lane >> 4) * 8);

  __shared__ __align__(16) __bf16 Abuf[2][BM * BK];   // 8 KB each, XOR-swizzled
  __shared__ float Ws[BM];

  const __bf16* aptr[2];
  int aoff[2];
  #pragma unroll
  for (int i = 0; i < 2; ++i) {
    int c = tid + i * 256, r = c >> 3, s = c & 7;
    int rr = (r < rem) ? r : (rem - 1);
    int base = soff + mt0 * BM + rr;
    int arow = ROUTED ? tok_list[base] : base;
    aptr[i] = A + (long)arow * K + s * 8;
    aoff[i] = r * 64 + ((s ^ (r & 7)) * 8);
  }

  f32x4 ag[4] = {}, au[4] = {};
  bf16x8 aR[2];
  f32x4 gA[4], gB[4], uA[4], uB[4];

#define LOAD_A(k) { _Pragma("unroll") \
  for (int i = 0; i < 2; ++i) aR[i] = *(const bf16x8*)(aptr[i] + (k)); }
#define STORE_A(b) { _Pragma("unroll") \
  for (int i = 0; i < 2; ++i) *(bf16x8*)&Abuf[b][aoff[i]] = aR[i]; }
#define LOAD_BP(ptr, dst, k) { \
  dst[0] = *(const f32x4*)(ptr + (k));      dst[1] = *(const f32x4*)(ptr + (k) + 4); \
  dst[2] = *(const f32x4*)(ptr + (k) + 32); dst[3] = *(const f32x4*)(ptr + (k) + 36); }
#define COMPUTE(gs, us, b) { _Pragma("unroll") \
  for (int ch = 0; ch < 2; ++ch) { \
    bf16x8 bg = cvt8(gs[ch*2], gs[ch*2+1]); \
    bf16x8 bu = cvt8(us[ch*2], us[ch*2+1]); \
    const int ro = ((lane & 15) * 64) + ((((ch*4) + (lane >> 4)) ^ (lane & 7)) * 8); \
    _Pragma("unroll") \
    for (int m = 0; m < 4; ++m) { \
      bf16x8 af = *(const bf16x8*)&Abuf[b][m * 1024 + ro]; \
      ag[m] = __builtin_amdgcn_mfma_f32_16x16x32_bf16(af, bg, ag[m], 0, 0, 0); \
      au[m] = __builtin_amdgcn_mfma_f32_16x16x32_bf16(af, bu, au[m], 0, 0, 0); \
    } \
  } }

  LOAD_A(0);
  LOAD_BP(Bg, gA, 0); LOAD_BP(Bu, uA, 0);
  const int NT = K / BK;                    // 32 (even)
  for (int t = 0; t < NT; t += 2) {
    const int k1 = (t + 1 < NT) ? (t + 1) * BK : 0;
    const int k2 = (t + 2 < NT) ? (t + 2) * BK : 0;
    STORE_A(0);
    LOAD_A(k1); LOAD_BP(Bg, gB, k1); LOAD_BP(Bu, uB, k1);
    BARRIER_NODRAIN();
    COMPUTE(gA, uA, 0);
    STORE_A(1);
    LOAD_A(k2); LOAD_BP(Bg, gA, k2); LOAD_BP(Bu, uA, k2);
    BARRIER_NODRAIN();
    COMPUTE(gB, uB, 1);
  }
#undef LOAD_A
#undef STORE_A
#undef LOAD_BP
#undef COMPUTE

  // epilogue: h = Ws[row] * silu(g) * u, LDS transpose, coalesced bf16x8 store
  if (tid < BM) {
    int rr = (tid < rem) ? tid : (rem - 1);
    Ws[tid] = ROUTED ? wgt_list[soff + mt0 * BM + rr] : 1.f;
  }
  __syncthreads();
  __bf16* Cs = &Abuf[0][0];
  #pragma unroll
  for (int m = 0; m < 4; ++m) {
    #pragma unroll
    for (int r = 0; r < 4; ++r) {
      int row = m * 16 + (lane >> 4) * 4 + r;
      float g = ag[m][r], u = au[m][r];
      float h = Ws[row] * g * u / (1.f + __expf(-g));
      Cs[row * 64 + wv * 16 + (lane & 15)] = (__bf16)h;
    }
  }
  __syncthreads();
  {
    int row = tid >> 2;
    if (row < rem) {
      __bf16* dst = Hout + (long)(soff + mt0 * BM + row) * ldh + blockIdx.x * BN_;
      #pragma unroll
      for (int j = 0; j < 2; ++j) {
        int c8 = (tid & 3) * 2 + j;
        *(bf16x8*)(dst + c8 * 8) = *(const bf16x8*)&Cs[row * 64 + c8 * 8];
      }
    }
  }
}

// ---------------- down streaming GEMM ----------------
// EPI 1: routed -> bf16 rows of y (per segment row, weight already in A)
// EPI 2: shared -> f32 stores into out
template<int EPI>
__global__ __launch_bounds__(256, 4)
void down_kernel(const __bf16* __restrict__ A, const float* __restrict__ B0,
                 long strideBe, int ldB, int K, void* __restrict__ Out, int ldc,
                 const int* __restrict__ pair_e, const int* __restrict__ pair_mt,
                 const int* __restrict__ npairs,
                 const int* __restrict__ seg_off, const int* __restrict__ seg_cnt,
                 int Mfull)
{
  const int tid  = threadIdx.x;
  const int lane = tid & 63;
  const int wv   = tid >> 6;

  int e, mt0, soff, cnt;
  if (EPI == 1) {
    int p = blockIdx.y;
    if (p >= npairs[0]) return;
    e = pair_e[p]; mt0 = pair_mt[p]; soff = seg_off[e]; cnt = seg_cnt[e];
  } else {
    e = 0; mt0 = blockIdx.y; soff = 0; cnt = Mfull;
  }
  const int rem = cnt - mt0 * BM;
  if (rem <= 0) return;

  const long bcol = (long)(blockIdx.x * BN_ + wv * 16 + (lane & 15));
  const float* Bp = B0 + (long)e * strideBe + bcol * ldB + ((lane >> 4) * 8);

  __shared__ __align__(16) __bf16 Abuf[2][BM * BK];

  const __bf16* aptr[2];
  int aoff[2];
  #pragma unroll
  for (int i = 0; i < 2; ++i) {
    int c = tid + i * 256, r = c >> 3, s = c & 7;
    int rr = (r < rem) ? r : (rem - 1);
    aptr[i] = A + (long)(soff + mt0 * BM + rr) * K + s * 8;
    aoff[i] = r * 64 + ((s ^ (r & 7)) * 8);
  }

  f32x4 acc[4] = {};
  bf16x8 aR[2];
  f32x4 bA[4], bB[4];

#define LOAD_A(k) { _Pragma("unroll") \
  for (int i = 0; i < 2; ++i) aR[i] = *(const bf16x8*)(aptr[i] + (k)); }
#define STORE_A(b) { _Pragma("unroll") \
  for (int i = 0; i < 2; ++i) *(bf16x8*)&Abuf[b][aoff[i]] = aR[i]; }
#define LOAD_B(dst, k) { \
  dst[0] = *(const f32x4*)(Bp + (k));      dst[1] = *(const f32x4*)(Bp + (k) + 4); \
  dst[2] = *(const f32x4*)(Bp + (k) + 32); dst[3] = *(const f32x4*)(Bp + (k) + 36); }
#define COMPUTE(bs, b) { _Pragma("unroll") \
  for (int ch = 0; ch < 2; ++ch) { \
    bf16x8 bfrag = cvt8(bs[ch*2], bs[ch*2+1]); \
    const int ro = ((lane & 15) * 64) + ((((ch*4) + (lane >> 4)) ^ (lane & 7)) * 8); \
    _Pragma("unroll") \
    for (int m = 0; m < 4; ++m) { \
      bf16x8 af = *(const bf16x8*)&Abuf[b][m * 1024 + ro]; \
      acc[m] = __builtin_amdgcn_mfma_f32_16x16x32_bf16(af, bfrag, acc[m], 0, 0, 0); \
    } \
  } }

  LOAD_A(0);
  LOAD_B(bA, 0);
  const int NT = K / BK;                    // 16 or 32 (even)
  for (int t = 0; t < NT; t += 2) {
    const int k1 = (t + 1 < NT) ? (t + 1) * BK : 0;
    const int k2 = (t + 2 < NT) ? (t + 2) * BK : 0;
    STORE_A(0);
    LOAD_A(k1); LOAD_B(bB, k1);
    BARRIER_NODRAIN();
    COMPUTE(bA, 0);
    STORE_A(1);
    LOAD_A(k2); LOAD_B(bA, k2);
    BARRIER_NODRAIN();
    COMPUTE(bB, 1);
  }
#undef LOAD_A
#undef STORE_A
#undef LOAD_B
#undef COMPUTE

  if (EPI == 1) {
    // bf16 y rows via LDS transpose
    __syncthreads();
    __bf16* Cs = &Abuf[0][0];
    #pragma unroll
    for (int m = 0; m < 4; ++m) {
      #pragma unroll
      for (int r = 0; r < 4; ++r) {
        int row = m * 16 + (lane >> 4) * 4 + r;
        Cs[row * 64 + wv * 16 + (lane & 15)] = (__bf16)acc[m][r];
      }
    }
    __syncthreads();
    int row = tid >> 2;
    if (row < rem) {
      __bf16* dst = (__bf16*)Out + (long)(soff + mt0 * BM + row) * ldc + blockIdx.x * BN_;
      #pragma unroll
      for (int j = 0; j < 2; ++j) {
        int c8 = (tid & 3) * 2 + j;
        *(bf16x8*)(dst + c8 * 8) = *(const bf16x8*)&Cs[row * 64 + c8 * 8];
      }
    }
  } else {
    float* O = (float*)Out;
    const int col = blockIdx.x * BN_ + wv * 16 + (lane & 15);
    #pragma unroll
    for (int m = 0; m < 4; ++m) {
      #pragma unroll
      for (int r = 0; r < 4; ++r) {
        int row = m * 16 + (lane >> 4) * 4 + r;
        if (row < rem)
          O[(long)(mt0 * BM + row) * ldc + col] = acc[m][r];
      }
    }
  }
}

// ---------------- combine: out[t] += sum_k y[pos(t,k)] ----------------
__global__ __launch_bounds__(256)
void combine_kernel(const __bf16* __restrict__ y, const int* __restrict__ pos_of,
                    float* __restrict__ out) {
  const int t = blockIdx.x;
  const int c0 = threadIdx.x * 8;
  float* orow = out + (long)t * HID + c0;
  f32x4 s0 = *(const f32x4*)orow;
  f32x4 s1 = *(const f32x4*)(orow + 4);
  #pragma unroll
  for (int k = 0; k < TOPK; ++k) {
    int row = pos_of[t * TOPK + k];
    bf16x8 v = *(const bf16x8*)(y + (long)row * HID + c0);
    s0[0] += (float)v[0]; s0[1] += (float)v[1]; s0[2] += (float)v[2]; s0[3] += (float)v[3];
    s1[0] += (float)v[4]; s1[1] += (float)v[5]; s1[2] += (float)v[6]; s1[3] += (float)v[7];
  }
  *(f32x4*)orow = s0;
  *(f32x4*)(orow + 4) = s1;
}

// ---------------- launch ----------------
extern "C" void kernel_launch(void* const* d_in, const int* in_sizes, int n_in,
                              void* d_out, int out_size, void* d_ws, size_t ws_size,
                              hipStream_t stream) {
  const float* x      = (const float*)d_in[0];
  const float* gate_w = (const float*)d_in[1];
  const float* e_bias = (const float*)d_in[2];
  const float* w_gate = (const float*)d_in[3];
  const float* w_up   = (const float*)d_in[4];
  const float* w_down = (const float*)d_in[5];
  const float* sw_gu  = (const float*)d_in[6];
  const float* sw_d   = (const float*)d_in[7];
  float* out = (float*)d_out;
  char* ws = (char*)d_ws;

  size_t off = 0;
  __bf16* x_bf = (__bf16*)(ws + off);        off += (size_t)T_TOK * HID * 2;   // 4 MB
  int*    ids  = (int*)(ws + off);           off += T_TOK * TOPK * 4;
  float*  wts  = (float*)(ws + off);         off += T_TOK * TOPK * 4;
  int* counts  = (int*)(ws + off);           off += 256;
  int* segoff  = (int*)(ws + off);           off += 256;
  int* cursors = (int*)(ws + off);           off += 256;
  int* pair_e  = (int*)(ws + off);           off += 1024;
  int* pair_mt = (int*)(ws + off);           off += 1024;
  int* npairs  = (int*)(ws + off);           off += 256;
  int* tok_list = (int*)(ws + off);          off += T_TOK * TOPK * 4;
  float* wgt_list = (float*)(ws + off);      off += T_TOK * TOPK * 4;
  int* pos_of  = (int*)(ws + off);           off += T_TOK * TOPK * 4;
  off = (off + 255) & ~(size_t)255;
  __bf16* h_buf  = (__bf16*)(ws + off);      off += (size_t)T_TOK * TOPK * IDIM * 2; // 16 MB
  __bf16* hs_buf = (__bf16*)(ws + off);      off += (size_t)T_TOK * ISH * 2;         // 4 MB
  __bf16* y_buf  = (__bf16*)(ws + off);      off += (size_t)T_TOK * TOPK * HID * 2;  // 32 MB

  init_kernel<<<1, 64, 0, stream>>>(counts);
  xcast_kernel<<<(T_TOK * HID) / (256 * 8), 256, 0, stream>>>(x, x_bf);
  router_kernel<<<T_TOK, 256, 0, stream>>>(x, gate_w, e_bias, ids, wts, counts);
  scan_kernel<<<1, 64, 0, stream>>>(counts, segoff, cursors, pair_e, pair_mt, npairs);
  scatter_kernel<<<(T_TOK * TOPK + 255) / 256, 256, 0, stream>>>(
      ids, wts, cursors, tok_list, wgt_list, pos_of);

  // routed fused gate+up -> h (weight folded)
  gu_kernel<true><<<dim3(IDIM / BN_, 256), 256, 0, stream>>>(
      x_bf, w_gate, w_up, (long)IDIM * HID, HID, HID, h_buf, IDIM,
      pair_e, pair_mt, npairs, segoff, counts, tok_list, wgt_list, 0);

  // shared fused gate+up -> hs
  gu_kernel<false><<<dim3(ISH / BN_, T_TOK / BM), 256, 0, stream>>>(
      x_bf, sw_gu, sw_gu + (size_t)ISH * HID, 0, HID, HID, hs_buf, ISH,
      nullptr, nullptr, nullptr, nullptr, nullptr, nullptr, nullptr, T_TOK);

  // shared down: writes out (initializes all of d_out)
  down_kernel<2><<<dim3(HID / BN_, T_TOK / BM), 256, 0, stream>>>(
      hs_buf, sw_d, 0, ISH, ISH, out, HID,
      nullptr, nullptr, nullptr, nullptr, nullptr, T_TOK);

  // routed down -> y rows (bf16, atomic-free)
  down_kernel<1><<<dim3(HID / BN_, 256), 256, 0, stream>>>(
      h_buf, w_down, (long)HID * IDIM, IDIM, IDIM, y_buf, HID,
      pair_e, pair_mt, npairs, segoff, counts, 0);

  // combine: out[t] += sum of this token's 8 y rows
  combine_kernel<<<T_TOK, 256, 0, stream>>>(y_buf, pos_of, out);
}

// Round 6
// 674.851 us; speedup vs baseline: 1.1612x; 1.1612x over previous
//
#include <hip/hip_runtime.h>
#include <hip/hip_bf16.h>
#include <math.h>

// Problem constants (match reference)
#define T_TOK 1024
#define HID   2048
#define NEXP  64
#define IDIM  1024
#define ISH   2048      // IS = I * N_SHARED
#define TOPK  8

typedef float  f32x4  __attribute__((ext_vector_type(4)));
typedef __bf16 bf16x8 __attribute__((ext_vector_type(8)));

#define BM  128
#define BN_ 64
#define BK  64

// Barrier that does NOT drain vmcnt (waits own DS ops only).
#define BARRIER_NODRAIN() asm volatile("s_waitcnt lgkmcnt(0)\n\ts_barrier" ::: "memory")

__device__ __forceinline__ bf16x8 cvt8(f32x4 a, f32x4 b) {
  bf16x8 v;
  v[0]=(__bf16)a[0]; v[1]=(__bf16)a[1]; v[2]=(__bf16)a[2]; v[3]=(__bf16)a[3];
  v[4]=(__bf16)b[0]; v[5]=(__bf16)b[1]; v[6]=(__bf16)b[2]; v[7]=(__bf16)b[3];
  return v;
}

// ---------------- init: zero expert counts ----------------
__global__ void init_kernel(int* counts) {
  if (threadIdx.x < NEXP) counts[threadIdx.x] = 0;
}

// ---------------- x (f32) -> x_bf16 ----------------
__global__ void xcast_kernel(const float* __restrict__ x, __bf16* __restrict__ xb) {
  long i = ((long)blockIdx.x * 256 + threadIdx.x) * 8;
  f32x4 a = *(const f32x4*)(x + i);
  f32x4 b = *(const f32x4*)(x + i + 4);
  *(bf16x8*)(xb + i) = cvt8(a, b);
}

// ---------------- router: logits + sigmoid + grouped top-k (f32) ----------------
__global__ __launch_bounds__(256)
void router_kernel(const float* __restrict__ x, const float* __restrict__ gw,
                   const float* __restrict__ eb,
                   int* __restrict__ ids, float* __restrict__ wts,
                   int* __restrict__ counts)
{
  __shared__ __align__(16) float xs[HID];
  __shared__ float red[256];
  __shared__ float sc[NEXP], sb[NEXP];
  const int t = blockIdx.x, tid = threadIdx.x;

  const f32x4* xsrc = (const f32x4*)(x + (long)t * HID);
  f32x4* xd = (f32x4*)xs;
  xd[tid]       = xsrc[tid];
  xd[tid + 256] = xsrc[tid + 256];
  __syncthreads();

  const int e = tid & 63, part = tid >> 6;
  const f32x4* wrow = (const f32x4*)(gw + (long)e * HID + part * 512);
  const f32x4* xrow = (const f32x4*)(xs + part * 512);
  float s = 0.f;
  #pragma unroll 4
  for (int j = 0; j < 128; ++j) {
    f32x4 wv = wrow[j], xv = xrow[j];
    s += wv[0]*xv[0] + wv[1]*xv[1] + wv[2]*xv[2] + wv[3]*xv[3];
  }
  red[tid] = s;
  __syncthreads();
  if (part == 0) {
    float logit = red[e] + red[e+64] + red[e+128] + red[e+192];
    float sig = 1.f / (1.f + expf(-logit));   // accurate exp: selection must match f32 ref
    sc[e] = sig; sb[e] = sig + eb[e];
  }
  __syncthreads();

  if (tid == 0) {
    float gsc[8];
    for (int g = 0; g < 8; ++g) {
      float m1 = -1e30f, m2 = -1e30f;
      for (int j = 0; j < 8; ++j) {
        float v = sb[g*8 + j];
        if (v > m1) { m2 = m1; m1 = v; } else if (v > m2) m2 = v;
      }
      gsc[g] = m1 + m2;
    }
    unsigned gmask = 0;
    for (int it = 0; it < 4; ++it) {
      int best = 0; float bv = -1e30f;
      for (int g = 0; g < 8; ++g)
        if (!((gmask >> g) & 1) && gsc[g] > bv) { bv = gsc[g]; best = g; }
      gmask |= 1u << best;
    }
    unsigned long long taken = 0;
    int id8[8]; float wsum = 0.f;
    for (int it = 0; it < 8; ++it) {
      int best = 0; float bv = -1e30f;
      for (int e2 = 0; e2 < 64; ++e2) {
        if (!((gmask >> (e2 >> 3)) & 1)) continue;
        if ((taken >> e2) & 1) continue;
        float v = sb[e2];
        if (v > bv) { bv = v; best = e2; }
      }
      taken |= 1ull << best;
      id8[it] = best; wsum += sc[best];
    }
    float inv = 2.5f / wsum;   // fold ROUTED_SCALE into weights
    for (int k = 0; k < 8; ++k) {
      ids[t*8 + k] = id8[k];
      wts[t*8 + k] = sc[id8[k]] * inv;
      atomicAdd(&counts[id8[k]], 1);
    }
  }
}

// ---------------- prefix scan + (expert, mt) pair worklist (BM=128 chunks) ----
__global__ void scan_kernel(const int* __restrict__ counts,
                            int* __restrict__ seg_off, int* __restrict__ cursors,
                            int* __restrict__ pair_e, int* __restrict__ pair_mt,
                            int* __restrict__ npairs) {
  if (threadIdx.x == 0) {
    int off = 0, np = 0;
    for (int e = 0; e < NEXP; ++e) {
      seg_off[e] = off; cursors[e] = off;
      int c = counts[e]; off += c;
      for (int m = 0; m * BM < c; ++m) { pair_e[np] = e; pair_mt[np] = m; ++np; }
    }
    npairs[0] = np;
  }
}

// ---------------- scatter (t, w) into per-expert segments ----------------
__global__ void scatter_kernel(const int* __restrict__ ids, const float* __restrict__ wts,
                               int* __restrict__ cursors,
                               int* __restrict__ tok_list, float* __restrict__ wgt_list,
                               int* __restrict__ pos_of) {
  int idx = blockIdx.x * 256 + threadIdx.x;
  if (idx >= T_TOK * TOPK) return;
  int t = idx >> 3;
  int e = ids[idx];
  int pos = atomicAdd(&cursors[e], 1);
  tok_list[pos] = t;
  wgt_list[pos] = wts[idx];
  pos_of[idx] = pos;
}

// ---------------- gate/up streaming GEMM (blockIdx.z picks stream) ----------
// Single B stream per block (round-3 proven pipeline, VGPR ~112). B per-wave
// global->reg->bf16 frag; A double-buffered swizzled LDS; no-drain barriers.
// Writes bf16 C (gathered-row A for ROUTED via tok_list).
template<bool ROUTED>
__global__ __launch_bounds__(256, 3)
void gu2_kernel(const __bf16* __restrict__ A,
                const float* __restrict__ Bg0, const float* __restrict__ Bu0,
                long strideBe, int ldB, int K,
                __bf16* __restrict__ Cg, __bf16* __restrict__ Cu, int ldc,
                const int* __restrict__ pair_e, const int* __restrict__ pair_mt,
                const int* __restrict__ npairs,
                const int* __restrict__ seg_off, const int* __restrict__ seg_cnt,
                const int* __restrict__ tok_list,
                int Mfull)
{
  const int tid  = threadIdx.x;
  const int lane = tid & 63;
  const int wv   = tid >> 6;

  int e, mt0, soff, cnt;
  if (ROUTED) {
    int p = blockIdx.y;
    if (p >= npairs[0]) return;
    e = pair_e[p]; mt0 = pair_mt[p]; soff = seg_off[e]; cnt = seg_cnt[e];
  } else {
    e = 0; mt0 = blockIdx.y; soff = 0; cnt = Mfull;
  }
  const int rem = cnt - mt0 * BM;
  if (rem <= 0) return;

  const float* B0 = blockIdx.z ? Bu0 : Bg0;
  __bf16* Cout    = blockIdx.z ? Cu  : Cg;

  // per-lane B row pointer: col = nt*64 + wv*16 + (lane&15), k-base (lane>>4)*8
  const float* Bp = B0 + (long)e * strideBe
                  + (long)(blockIdx.x * BN_ + wv * 16 + (lane & 15)) * ldB
                  + ((lane >> 4) * 8);

  __shared__ __align__(16) __bf16 Abuf[2][BM * BK];   // 16 KB each, XOR-swizzled

  // A staging: 4 chunks of bf16x8 per thread per K-step
  const __bf16* aptr[4];
  int aoff[4];
  #pragma unroll
  for (int i = 0; i < 4; ++i) {
    int c = tid + i * 256, r = c >> 3, s = c & 7;
    int rr = (r < rem) ? r : (rem - 1);
    int base = soff + mt0 * BM + rr;
    int arow = ROUTED ? tok_list[base] : base;
    aptr[i] = A + (long)arow * K + s * 8;
    aoff[i] = r * 64 + ((s ^ (r & 7)) * 8);           // swizzle: slot ^= row&7
  }

  f32x4 acc[8] = {};
  bf16x8 aR[4];
  f32x4 bA[4], bB[4];

#define LOAD_A(k) { _Pragma("unroll") \
  for (int i = 0; i < 4; ++i) aR[i] = *(const bf16x8*)(aptr[i] + (k)); }
#define STORE_A(b) { _Pragma("unroll") \
  for (int i = 0; i < 4; ++i) *(bf16x8*)&Abuf[b][aoff[i]] = aR[i]; }
#define LOAD_B(dst, k) { \
  dst[0] = *(const f32x4*)(Bp + (k));      dst[1] = *(const f32x4*)(Bp + (k) + 4); \
  dst[2] = *(const f32x4*)(Bp + (k) + 32); dst[3] = *(const f32x4*)(Bp + (k) + 36); }
#define COMPUTE(bsrc, b) { _Pragma("unroll") \
  for (int ch = 0; ch < 2; ++ch) { \
    bf16x8 bfrag = cvt8(bsrc[ch*2], bsrc[ch*2+1]); \
    const int ro = ((lane & 15) * 64) + ((((ch*4) + (lane >> 4)) ^ (lane & 7)) * 8); \
    _Pragma("unroll") \
    for (int m = 0; m < 8; ++m) { \
      bf16x8 af = *(const bf16x8*)&Abuf[b][m * 1024 + ro]; \
      acc[m] = __builtin_amdgcn_mfma_f32_16x16x32_bf16(af, bfrag, acc[m], 0, 0, 0); \
    } \
  } }

  LOAD_A(0);
  LOAD_B(bA, 0);
  const int NT = K / BK;                   // 32 (even)
  for (int t = 0; t < NT; t += 2) {
    const int k1 = (t + 1 < NT) ? (t + 1) * BK : 0;
    const int k2 = (t + 2 < NT) ? (t + 2) * BK : 0;
    STORE_A(0);
    LOAD_A(k1); LOAD_B(bB, k1);            // stay in flight across barrier+compute
    BARRIER_NODRAIN();
    COMPUTE(bA, 0);
    STORE_A(1);
    LOAD_A(k2); LOAD_B(bA, k2);
    BARRIER_NODRAIN();
    COMPUTE(bB, 1);
  }
#undef LOAD_A
#undef STORE_A
#undef LOAD_B
#undef COMPUTE

  // LDS transpose for coalesced bf16x8 stores
  __syncthreads();
  __bf16* Cs = &Abuf[0][0];
  #pragma unroll
  for (int m = 0; m < 8; ++m) {
    #pragma unroll
    for (int r = 0; r < 4; ++r) {
      int row = m * 16 + (lane >> 4) * 4 + r;
      Cs[row * 64 + wv * 16 + (lane & 15)] = (__bf16)acc[m][r];
    }
  }
  __syncthreads();
  #pragma unroll
  for (int p = 0; p < 4; ++p) {
    int row = p * 32 + (tid >> 3);
    if (row < rem)
      *(bf16x8*)(Cout + (long)(soff + mt0 * BM + row) * ldc + blockIdx.x * BN_ + (tid & 7) * 8) =
          *(const bf16x8*)&Cs[row * 64 + (tid & 7) * 8];
  }
}

// ---------------- down streaming GEMM ----------------
// EPI 1: routed -> bf16 seg-ordered rows of y (no gather; weight already in h)
// EPI 2: shared -> f32 stores into out
template<int EPI>
__global__ __launch_bounds__(256, 3)
void down_kernel(const __bf16* __restrict__ A, const float* __restrict__ B0,
                 long strideBe, int ldB, int K, void* __restrict__ Out, int ldc,
                 const int* __restrict__ pair_e, const int* __restrict__ pair_mt,
                 const int* __restrict__ npairs,
                 const int* __restrict__ seg_off, const int* __restrict__ seg_cnt,
                 int Mfull)
{
  const int tid  = threadIdx.x;
  const int lane = tid & 63;
  const int wv   = tid >> 6;

  int e, mt0, soff, cnt;
  if (EPI == 1) {
    int p = blockIdx.y;
    if (p >= npairs[0]) return;
    e = pair_e[p]; mt0 = pair_mt[p]; soff = seg_off[e]; cnt = seg_cnt[e];
  } else {
    e = 0; mt0 = blockIdx.y; soff = 0; cnt = Mfull;
  }
  const int rem = cnt - mt0 * BM;
  if (rem <= 0) return;

  const float* Bp = B0 + (long)e * strideBe
                  + (long)(blockIdx.x * BN_ + wv * 16 + (lane & 15)) * ldB
                  + ((lane >> 4) * 8);

  __shared__ __align__(16) __bf16 Abuf[2][BM * BK];

  const __bf16* aptr[4];
  int aoff[4];
  #pragma unroll
  for (int i = 0; i < 4; ++i) {
    int c = tid + i * 256, r = c >> 3, s = c & 7;
    int rr = (r < rem) ? r : (rem - 1);
    aptr[i] = A + (long)(soff + mt0 * BM + rr) * K + s * 8;
    aoff[i] = r * 64 + ((s ^ (r & 7)) * 8);
  }

  f32x4 acc[8] = {};
  bf16x8 aR[4];
  f32x4 bA[4], bB[4];

#define LOAD_A(k) { _Pragma("unroll") \
  for (int i = 0; i < 4; ++i) aR[i] = *(const bf16x8*)(aptr[i] + (k)); }
#define STORE_A(b) { _Pragma("unroll") \
  for (int i = 0; i < 4; ++i) *(bf16x8*)&Abuf[b][aoff[i]] = aR[i]; }
#define LOAD_B(dst, k) { \
  dst[0] = *(const f32x4*)(Bp + (k));      dst[1] = *(const f32x4*)(Bp + (k) + 4); \
  dst[2] = *(const f32x4*)(Bp + (k) + 32); dst[3] = *(const f32x4*)(Bp + (k) + 36); }
#define COMPUTE(bs, b) { _Pragma("unroll") \
  for (int ch = 0; ch < 2; ++ch) { \
    bf16x8 bfrag = cvt8(bs[ch*2], bs[ch*2+1]); \
    const int ro = ((lane & 15) * 64) + ((((ch*4) + (lane >> 4)) ^ (lane & 7)) * 8); \
    _Pragma("unroll") \
    for (int m = 0; m < 8; ++m) { \
      bf16x8 af = *(const bf16x8*)&Abuf[b][m * 1024 + ro]; \
      acc[m] = __builtin_amdgcn_mfma_f32_16x16x32_bf16(af, bfrag, acc[m], 0, 0, 0); \
    } \
  } }

  LOAD_A(0);
  LOAD_B(bA, 0);
  const int NT = K / BK;                    // 16 or 32 (even)
  for (int t = 0; t < NT; t += 2) {
    const int k1 = (t + 1 < NT) ? (t + 1) * BK : 0;
    const int k2 = (t + 2 < NT) ? (t + 2) * BK : 0;
    STORE_A(0);
    LOAD_A(k1); LOAD_B(bB, k1);
    BARRIER_NODRAIN();
    COMPUTE(bA, 0);
    STORE_A(1);
    LOAD_A(k2); LOAD_B(bA, k2);
    BARRIER_NODRAIN();
    COMPUTE(bB, 1);
  }
#undef LOAD_A
#undef STORE_A
#undef LOAD_B
#undef COMPUTE

  if (EPI == 1) {
    // bf16 y rows via LDS transpose (coalesced bf16x8 stores)
    __syncthreads();
    __bf16* Cs = &Abuf[0][0];
    #pragma unroll
    for (int m = 0; m < 8; ++m) {
      #pragma unroll
      for (int r = 0; r < 4; ++r) {
        int row = m * 16 + (lane >> 4) * 4 + r;
        Cs[row * 64 + wv * 16 + (lane & 15)] = (__bf16)acc[m][r];
      }
    }
    __syncthreads();
    #pragma unroll
    for (int p = 0; p < 4; ++p) {
      int row = p * 32 + (tid >> 3);
      if (row < rem)
        *(bf16x8*)((__bf16*)Out + (long)(soff + mt0 * BM + row) * ldc + blockIdx.x * BN_ + (tid & 7) * 8) =
            *(const bf16x8*)&Cs[row * 64 + (tid & 7) * 8];
    }
  } else {
    float* O = (float*)Out;
    const int col = blockIdx.x * BN_ + wv * 16 + (lane & 15);
    #pragma unroll
    for (int m = 0; m < 8; ++m) {
      #pragma unroll
      for (int r = 0; r < 4; ++r) {
        int row = m * 16 + (lane >> 4) * 4 + r;
        if (row < rem)
          O[(long)(mt0 * BM + row) * ldc + col] = acc[m][r];
      }
    }
  }
}

// ---------------- fuse: h = silu(g) * u * w  (in place into g) ----------------
__global__ void fuse_kernel(__bf16* __restrict__ g, const __bf16* __restrict__ u,
                            const float* __restrict__ wrow, int rshift) {
  long idx = ((long)blockIdx.x * 256 + threadIdx.x) * 8;
  bf16x8 gv = *(bf16x8*)(g + idx);
  bf16x8 uv = *(const bf16x8*)(u + idx);
  float w = wrow ? wrow[idx >> rshift] : 1.f;
  bf16x8 h;
  #pragma unroll
  for (int j = 0; j < 8; ++j) {
    float gf = (float)gv[j], uf = (float)uv[j];
    h[j] = (__bf16)(w * gf * uf / (1.f + __expf(-gf)));
  }
  *(bf16x8*)(g + idx) = h;
}

// ---------------- combine: out[t] += sum_k y[pos(t,k)] ----------------
__global__ __launch_bounds__(256)
void combine_kernel(const __bf16* __restrict__ y, const int* __restrict__ pos_of,
                    float* __restrict__ out) {
  const int t = blockIdx.x;
  const int c0 = threadIdx.x * 8;
  float* orow = out + (long)t * HID + c0;
  f32x4 s0 = *(const f32x4*)orow;
  f32x4 s1 = *(const f32x4*)(orow + 4);
  #pragma unroll
  for (int k = 0; k < TOPK; ++k) {
    int row = pos_of[t * TOPK + k];
    bf16x8 v = *(const bf16x8*)(y + (long)row * HID + c0);
    s0[0] += (float)v[0]; s0[1] += (float)v[1]; s0[2] += (float)v[2]; s0[3] += (float)v[3];
    s1[0] += (float)v[4]; s1[1] += (float)v[5]; s1[2] += (float)v[6]; s1[3] += (float)v[7];
  }
  *(f32x4*)orow = s0;
  *(f32x4*)(orow + 4) = s1;
}

// ---------------- launch ----------------
extern "C" void kernel_launch(void* const* d_in, const int* in_sizes, int n_in,
                              void* d_out, int out_size, void* d_ws, size_t ws_size,
                              hipStream_t stream) {
  const float* x      = (const float*)d_in[0];
  const float* gate_w = (const float*)d_in[1];
  const float* e_bias = (const float*)d_in[2];
  const float* w_gate = (const float*)d_in[3];
  const float* w_up   = (const float*)d_in[4];
  const float* w_down = (const float*)d_in[5];
  const float* sw_gu  = (const float*)d_in[6];
  const float* sw_d   = (const float*)d_in[7];
  float* out = (float*)d_out;
  char* ws = (char*)d_ws;

  size_t off = 0;
  __bf16* x_bf = (__bf16*)(ws + off);        off += (size_t)T_TOK * HID * 2;   // 4 MB
  int*    ids  = (int*)(ws + off);           off += T_TOK * TOPK * 4;
  float*  wts  = (float*)(ws + off);         off += T_TOK * TOPK * 4;
  int* counts  = (int*)(ws + off);           off += 256;
  int* segoff  = (int*)(ws + off);           off += 256;
  int* cursors = (int*)(ws + off);           off += 256;
  int* pair_e  = (int*)(ws + off);           off += 1024;
  int* pair_mt = (int*)(ws + off);           off += 1024;
  int* npairs  = (int*)(ws + off);           off += 256;
  int* tok_list = (int*)(ws + off);          off += T_TOK * TOPK * 4;
  float* wgt_list = (float*)(ws + off);      off += T_TOK * TOPK * 4;
  int* pos_of  = (int*)(ws + off);           off += T_TOK * TOPK * 4;
  off = (off + 255) & ~(size_t)255;
  __bf16* g_buf  = (__bf16*)(ws + off);      off += (size_t)T_TOK * TOPK * IDIM * 2; // 16 MB
  __bf16* u_buf  = (__bf16*)(ws + off);      off += (size_t)T_TOK * TOPK * IDIM * 2; // 16 MB
  __bf16* gs_buf = (__bf16*)(ws + off);      off += (size_t)T_TOK * ISH * 2;         // 4 MB
  __bf16* us_buf = (__bf16*)(ws + off);      off += (size_t)T_TOK * ISH * 2;         // 4 MB
  __bf16* y_buf  = (__bf16*)(ws + off);      off += (size_t)T_TOK * TOPK * HID * 2;  // 32 MB

  init_kernel<<<1, 64, 0, stream>>>(counts);
  xcast_kernel<<<(T_TOK * HID) / (256 * 8), 256, 0, stream>>>(x, x_bf);
  router_kernel<<<T_TOK, 256, 0, stream>>>(x, gate_w, e_bias, ids, wts, counts);
  scan_kernel<<<1, 64, 0, stream>>>(counts, segoff, cursors, pair_e, pair_mt, npairs);
  scatter_kernel<<<(T_TOK * TOPK + 255) / 256, 256, 0, stream>>>(
      ids, wts, cursors, tok_list, wgt_list, pos_of);

  // routed gate (z=0) + up (z=1), one dispatch, single-stream blocks
  gu2_kernel<true><<<dim3(IDIM / BN_, 128, 2), 256, 0, stream>>>(
      x_bf, w_gate, w_up, (long)IDIM * HID, HID, HID, g_buf, u_buf, IDIM,
      pair_e, pair_mt, npairs, segoff, counts, tok_list, 0);

  // h = silu(g)*u*w  (w includes ROUTED_SCALE and renorm)
  fuse_kernel<<<(T_TOK * TOPK * IDIM) / (256 * 8), 256, 0, stream>>>(g_buf, u_buf, wgt_list, 10);

  // shared gate (z=0) + up (z=1)
  gu2_kernel<false><<<dim3(ISH / BN_, T_TOK / BM, 2), 256, 0, stream>>>(
      x_bf, sw_gu, sw_gu + (size_t)ISH * HID, 0, HID, HID, gs_buf, us_buf, ISH,
      nullptr, nullptr, nullptr, nullptr, nullptr, nullptr, T_TOK);
  fuse_kernel<<<(T_TOK * ISH) / (256 * 8), 256, 0, stream>>>(gs_buf, us_buf, nullptr, 11);

  // shared down: writes out (initializes all of d_out)
  down_kernel<2><<<dim3(HID / BN_, T_TOK / BM), 256, 0, stream>>>(
      gs_buf, sw_d, 0, ISH, ISH, out, HID,
      nullptr, nullptr, nullptr, nullptr, nullptr, T_TOK);

  // routed down -> y rows (bf16, atomic-free, segment-ordered)
  down_kernel<1><<<dim3(HID / BN_, 128), 256, 0, stream>>>(
      g_buf, w_down, (long)HID * IDIM, IDIM, IDIM, y_buf, HID,
      pair_e, pair_mt, npairs, segoff, counts, 0);

  // combine: out[t] += sum of this token's 8 y rows
  combine_kernel<<<T_TOK, 256, 0, stream>>>(y_buf, pos_of, out);
}

// Round 7
// 653.401 us; speedup vs baseline: 1.1993x; 1.0328x over previous
//
#include <hip/hip_runtime.h>
#include <hip/hip_bf16.h>
#include <math.h>

// Problem constants (match reference)
#define T_TOK 1024
#define HID   2048
#define NEXP  64
#define IDIM  1024
#define ISH   2048      // IS = I * N_SHARED
#define TOPK  8

typedef float  f32x4  __attribute__((ext_vector_type(4)));
typedef __bf16 bf16x8 __attribute__((ext_vector_type(8)));

#define BM  128
#define BN_ 64
#define BK  64

// Barrier that does NOT drain vmcnt (waits own DS ops only).
#define BARRIER_NODRAIN() asm volatile("s_waitcnt lgkmcnt(0)\n\ts_barrier" ::: "memory")

__device__ __forceinline__ bf16x8 cvt8(f32x4 a, f32x4 b) {
  bf16x8 v;
  v[0]=(__bf16)a[0]; v[1]=(__bf16)a[1]; v[2]=(__bf16)a[2]; v[3]=(__bf16)a[3];
  v[4]=(__bf16)b[0]; v[5]=(__bf16)b[1]; v[6]=(__bf16)b[2]; v[7]=(__bf16)b[3];
  return v;
}

// ---------------- init: zero expert counts ----------------
__global__ void init_kernel(int* counts) {
  if (threadIdx.x < NEXP) counts[threadIdx.x] = 0;
}

// ---------------- x (f32) -> x_bf16 ----------------
__global__ void xcast_kernel(const float* __restrict__ x, __bf16* __restrict__ xb) {
  long i = ((long)blockIdx.x * 256 + threadIdx.x) * 8;
  f32x4 a = *(const f32x4*)(x + i);
  f32x4 b = *(const f32x4*)(x + i + 4);
  *(bf16x8*)(xb + i) = cvt8(a, b);
}

// ---------------- router: logits + sigmoid + grouped top-k (f32) ----------------
__global__ __launch_bounds__(256)
void router_kernel(const float* __restrict__ x, const float* __restrict__ gw,
                   const float* __restrict__ eb,
                   int* __restrict__ ids, float* __restrict__ wts,
                   int* __restrict__ counts)
{
  __shared__ __align__(16) float xs[HID];
  __shared__ float red[256];
  __shared__ float sc[NEXP], sb[NEXP];
  const int t = blockIdx.x, tid = threadIdx.x;

  const f32x4* xsrc = (const f32x4*)(x + (long)t * HID);
  f32x4* xd = (f32x4*)xs;
  xd[tid]       = xsrc[tid];
  xd[tid + 256] = xsrc[tid + 256];
  __syncthreads();

  const int e = tid & 63, part = tid >> 6;
  const f32x4* wrow = (const f32x4*)(gw + (long)e * HID + part * 512);
  const f32x4* xrow = (const f32x4*)(xs + part * 512);
  float s = 0.f;
  #pragma unroll 4
  for (int j = 0; j < 128; ++j) {
    f32x4 wv = wrow[j], xv = xrow[j];
    s += wv[0]*xv[0] + wv[1]*xv[1] + wv[2]*xv[2] + wv[3]*xv[3];
  }
  red[tid] = s;
  __syncthreads();
  if (part == 0) {
    float logit = red[e] + red[e+64] + red[e+128] + red[e+192];
    float sig = 1.f / (1.f + expf(-logit));   // accurate exp: selection must match f32 ref
    sc[e] = sig; sb[e] = sig + eb[e];
  }
  __syncthreads();

  if (tid == 0) {
    float gsc[8];
    for (int g = 0; g < 8; ++g) {
      float m1 = -1e30f, m2 = -1e30f;
      for (int j = 0; j < 8; ++j) {
        float v = sb[g*8 + j];
        if (v > m1) { m2 = m1; m1 = v; } else if (v > m2) m2 = v;
      }
      gsc[g] = m1 + m2;
    }
    unsigned gmask = 0;
    for (int it = 0; it < 4; ++it) {
      int best = 0; float bv = -1e30f;
      for (int g = 0; g < 8; ++g)
        if (!((gmask >> g) & 1) && gsc[g] > bv) { bv = gsc[g]; best = g; }
      gmask |= 1u << best;
    }
    unsigned long long taken = 0;
    int id8[8]; float wsum = 0.f;
    for (int it = 0; it < 8; ++it) {
      int best = 0; float bv = -1e30f;
      for (int e2 = 0; e2 < 64; ++e2) {
        if (!((gmask >> (e2 >> 3)) & 1)) continue;
        if ((taken >> e2) & 1) continue;
        float v = sb[e2];
        if (v > bv) { bv = v; best = e2; }
      }
      taken |= 1ull << best;
      id8[it] = best; wsum += sc[best];
    }
    float inv = 2.5f / wsum;   // fold ROUTED_SCALE into weights
    for (int k = 0; k < 8; ++k) {
      ids[t*8 + k] = id8[k];
      wts[t*8 + k] = sc[id8[k]] * inv;
      atomicAdd(&counts[id8[k]], 1);
    }
  }
}

// ---------------- prefix scan + (expert, mt) pair worklist (BM=128 chunks) ----
__global__ void scan_kernel(const int* __restrict__ counts,
                            int* __restrict__ seg_off, int* __restrict__ cursors,
                            int* __restrict__ pair_e, int* __restrict__ pair_mt,
                            int* __restrict__ npairs) {
  if (threadIdx.x == 0) {
    int off = 0, np = 0;
    for (int e = 0; e < NEXP; ++e) {
      seg_off[e] = off; cursors[e] = off;
      int c = counts[e]; off += c;
      for (int m = 0; m * BM < c; ++m) { pair_e[np] = e; pair_mt[np] = m; ++np; }
    }
    npairs[0] = np;
  }
}

// ---------------- scatter (t, w) into per-expert segments ----------------
__global__ void scatter_kernel(const int* __restrict__ ids, const float* __restrict__ wts,
                               int* __restrict__ cursors,
                               int* __restrict__ tok_list, float* __restrict__ wgt_list,
                               int* __restrict__ pos_of) {
  int idx = blockIdx.x * 256 + threadIdx.x;
  if (idx >= T_TOK * TOPK) return;
  int t = idx >> 3;
  int e = ids[idx];
  int pos = atomicAdd(&cursors[e], 1);
  tok_list[pos] = t;
  wgt_list[pos] = wts[idx];
  pos_of[idx] = pos;
}

// ---------------- DMA streaming GEMM ----------------
// A (bf16 [*,K], optionally row-gathered) and B (f32 [N,K]) both staged via
// global_load_lds(16B): linear LDS dest, inverse-XOR-swizzled global source,
// swizzled ds_read (2-way max bank aliasing). 3-deep buffer rotation, one
// no-drain barrier per K-step, counted vmcnt(8) -> stage(t), stage(t+1)
// always in flight, stage(t+2) issued before compute(t).
// LDS/buf: A 16 KB + B(f32) 16 KB; 3 bufs = 96 KB -> 1 block/CU.
// blockIdx.z (when gridDim.z==2) picks Bg0/Cg vs Bu0/Cu (gate vs up).
// EPI 0: bf16 C store via LDS transpose. EPI 2: f32 direct store.
template<int EPI, bool ROUTED, bool GATHER>
__global__ __launch_bounds__(256, 1)
void gemm_dma(const __bf16* __restrict__ A, const float* __restrict__ Bg0,
              const float* __restrict__ Bu0, long strideBe, int ldB, int K,
              void* Cg, void* Cu, int ldc,
              const int* __restrict__ pair_e, const int* __restrict__ pair_mt,
              const int* __restrict__ npairs,
              const int* __restrict__ seg_off, const int* __restrict__ seg_cnt,
              const int* __restrict__ tok_list, int Mfull)
{
  __shared__ __align__(16) char smem[3 * 32768];
  const int tid = threadIdx.x, lane = tid & 63, wv = tid >> 6;

  int e, mt0, soff, cnt;
  if (ROUTED) {
    int p = blockIdx.y;
    if (p >= npairs[0]) return;
    e = pair_e[p]; mt0 = pair_mt[p]; soff = seg_off[e]; cnt = seg_cnt[e];
  } else {
    e = 0; mt0 = blockIdx.y; soff = 0; cnt = Mfull;
  }
  const int rem = cnt - mt0 * BM;
  if (rem <= 0) return;

  const float* B0 = (gridDim.z == 2 && blockIdx.z) ? Bu0 : Bg0;
  void* Cout      = (gridDim.z == 2 && blockIdx.z) ? Cu  : Cg;
  const float* Bb0 = B0 + (long)e * strideBe;

  // staging sources: per lane, 4 A-chunks (row, kc^row) and 4 B-chunks (col, kc^col)
  const __bf16* srcA[4];
  const float*  srcB[4];
  #pragma unroll
  for (int i = 0; i < 4; ++i) {
    int row = wv * 32 + i * 8 + (lane >> 3);
    int kcA = (lane & 7) ^ (row & 7);
    int rr  = (row < rem) ? row : (rem - 1);
    int idx = soff + mt0 * BM + rr;
    long arow = GATHER ? (long)tok_list[idx] : (long)idx;
    srcA[i] = A + arow * (long)K + kcA * 8;

    int col = wv * 16 + i * 4 + (lane >> 4);
    int kcB = (lane & 15) ^ (col & 15);
    srcB[i] = Bb0 + (long)(blockIdx.x * BN_ + col) * ldB + kcB * 4;
  }

#define STAGE(b, kk) { \
  char* Ad = smem + (b) * 32768 + wv * 4096; \
  char* Bd = Ad + 16384; \
  _Pragma("unroll") \
  for (int i = 0; i < 4; ++i) \
    __builtin_amdgcn_global_load_lds((const __attribute__((address_space(1))) void*)(srcA[i] + (kk)), \
        (__attribute__((address_space(3))) void*)(Ad + i * 1024), 16, 0, 0); \
  _Pragma("unroll") \
  for (int i = 0; i < 4; ++i) \
    __builtin_amdgcn_global_load_lds((const __attribute__((address_space(1))) void*)(srcB[i] + (kk)), \
        (__attribute__((address_space(3))) void*)(Bd + i * 1024), 16, 0, 0); }

  f32x4 acc[8] = {};
  const int c15 = lane & 15, hi = lane >> 4;

#define COMPUTE(b) { \
  char* Ab = smem + (b) * 32768; \
  char* Bbuf = Ab + 16384; \
  _Pragma("unroll") \
  for (int kh = 0; kh < 2; ++kh) { \
    const int colL = wv * 16 + c15; \
    const int kc = kh * 8 + hi * 2; \
    f32x4 b0 = *(const f32x4*)(Bbuf + colL * 256 + (((kc    ) ^ c15) << 4)); \
    f32x4 b1 = *(const f32x4*)(Bbuf + colL * 256 + (((kc + 1) ^ c15) << 4)); \
    bf16x8 bfrag = cvt8(b0, b1); \
    const int physA = ((kh * 4 + hi) ^ (lane & 7)) << 4; \
    _Pragma("unroll") \
    for (int m = 0; m < 8; ++m) { \
      bf16x8 af = *(const bf16x8*)(Ab + (m * 16 + c15) * 128 + physA); \
      acc[m] = __builtin_amdgcn_mfma_f32_16x16x32_bf16(af, bfrag, acc[m], 0, 0, 0); \
    } \
  } }

  const int NT = K / BK;
  STAGE(0, 0);
  STAGE(1, BK);
  for (int t = 0; t < NT; ++t) {
    asm volatile("s_waitcnt vmcnt(8)" ::: "memory");   // stage(t) landed; t+1 in flight
    BARRIER_NODRAIN();                                  // all waves done reading buf (t+2)%3
    const int kk = (t + 2 < NT) ? (t + 2) * BK : 0;     // tail: dummy re-stage (k=0)
    STAGE((t + 2) % 3, kk);
    COMPUTE(t % 3);
  }
#undef STAGE
#undef COMPUTE

  // drain dummy DMA (may target buf0 = transpose scratch), then sync
  asm volatile("s_waitcnt vmcnt(0)" ::: "memory");
  BARRIER_NODRAIN();

  if (EPI == 0) {
    __bf16* Cs = (__bf16*)smem;
    #pragma unroll
    for (int m = 0; m < 8; ++m) {
      #pragma unroll
      for (int r = 0; r < 4; ++r) {
        int row = m * 16 + hi * 4 + r;
        Cs[row * 64 + wv * 16 + c15] = (__bf16)acc[m][r];
      }
    }
    BARRIER_NODRAIN();
    __bf16* Cb = (__bf16*)Cout;
    #pragma unroll
    for (int p = 0; p < 4; ++p) {
      int row = p * 32 + (tid >> 3);
      if (row < rem)
        *(bf16x8*)(Cb + (long)(soff + mt0 * BM + row) * ldc + blockIdx.x * BN_ + (tid & 7) * 8) =
            *(const bf16x8*)&Cs[row * 64 + (tid & 7) * 8];
    }
  } else {
    float* O = (float*)Cout;
    const int col = blockIdx.x * BN_ + wv * 16 + c15;
    #pragma unroll
    for (int m = 0; m < 8; ++m) {
      #pragma unroll
      for (int r = 0; r < 4; ++r) {
        int row = m * 16 + hi * 4 + r;
        if (row < rem)
          O[(long)(mt0 * BM + row) * ldc + col] = acc[m][r];
      }
    }
  }
}

// ---------------- fuse: h = silu(g) * u * w  (in place into g) ----------------
__global__ void fuse_kernel(__bf16* __restrict__ g, const __bf16* __restrict__ u,
                            const float* __restrict__ wrow, int rshift) {
  long idx = ((long)blockIdx.x * 256 + threadIdx.x) * 8;
  bf16x8 gv = *(bf16x8*)(g + idx);
  bf16x8 uv = *(const bf16x8*)(u + idx);
  float w = wrow ? wrow[idx >> rshift] : 1.f;
  bf16x8 h;
  #pragma unroll
  for (int j = 0; j < 8; ++j) {
    float gf = (float)gv[j], uf = (float)uv[j];
    h[j] = (__bf16)(w * gf * uf / (1.f + __expf(-gf)));
  }
  *(bf16x8*)(g + idx) = h;
}

// ---------------- combine: out[t] += sum_k y[pos(t,k)] ----------------
__global__ __launch_bounds__(256)
void combine_kernel(const __bf16* __restrict__ y, const int* __restrict__ pos_of,
                    float* __restrict__ out) {
  const int t = blockIdx.x;
  const int c0 = threadIdx.x * 8;
  float* orow = out + (long)t * HID + c0;
  f32x4 s0 = *(const f32x4*)orow;
  f32x4 s1 = *(const f32x4*)(orow + 4);
  #pragma unroll
  for (int k = 0; k < TOPK; ++k) {
    int row = pos_of[t * TOPK + k];
    bf16x8 v = *(const bf16x8*)(y + (long)row * HID + c0);
    s0[0] += (float)v[0]; s0[1] += (float)v[1]; s0[2] += (float)v[2]; s0[3] += (float)v[3];
    s1[0] += (float)v[4]; s1[1] += (float)v[5]; s1[2] += (float)v[6]; s1[3] += (float)v[7];
  }
  *(f32x4*)orow = s0;
  *(f32x4*)(orow + 4) = s1;
}

// ---------------- launch ----------------
extern "C" void kernel_launch(void* const* d_in, const int* in_sizes, int n_in,
                              void* d_out, int out_size, void* d_ws, size_t ws_size,
                              hipStream_t stream) {
  const float* x      = (const float*)d_in[0];
  const float* gate_w = (const float*)d_in[1];
  const float* e_bias = (const float*)d_in[2];
  const float* w_gate = (const float*)d_in[3];
  const float* w_up   = (const float*)d_in[4];
  const float* w_down = (const float*)d_in[5];
  const float* sw_gu  = (const float*)d_in[6];
  const float* sw_d   = (const float*)d_in[7];
  float* out = (float*)d_out;
  char* ws = (char*)d_ws;

  size_t off = 0;
  __bf16* x_bf = (__bf16*)(ws + off);        off += (size_t)T_TOK * HID * 2;   // 4 MB
  int*    ids  = (int*)(ws + off);           off += T_TOK * TOPK * 4;
  float*  wts  = (float*)(ws + off);         off += T_TOK * TOPK * 4;
  int* counts  = (int*)(ws + off);           off += 256;
  int* segoff  = (int*)(ws + off);           off += 256;
  int* cursors = (int*)(ws + off);           off += 256;
  int* pair_e  = (int*)(ws + off);           off += 1024;
  int* pair_mt = (int*)(ws + off);           off += 1024;
  int* npairs  = (int*)(ws + off);           off += 256;
  int* tok_list = (int*)(ws + off);          off += T_TOK * TOPK * 4;
  float* wgt_list = (float*)(ws + off);      off += T_TOK * TOPK * 4;
  int* pos_of  = (int*)(ws + off);           off += T_TOK * TOPK * 4;
  off = (off + 255) & ~(size_t)255;
  __bf16* g_buf  = (__bf16*)(ws + off);      off += (size_t)T_TOK * TOPK * IDIM * 2; // 16 MB
  __bf16* u_buf  = (__bf16*)(ws + off);      off += (size_t)T_TOK * TOPK * IDIM * 2; // 16 MB
  __bf16* gs_buf = (__bf16*)(ws + off);      off += (size_t)T_TOK * ISH * 2;         // 4 MB
  __bf16* us_buf = (__bf16*)(ws + off);      off += (size_t)T_TOK * ISH * 2;         // 4 MB
  __bf16* y_buf  = (__bf16*)(ws + off);      off += (size_t)T_TOK * TOPK * HID * 2;  // 32 MB

  init_kernel<<<1, 64, 0, stream>>>(counts);
  xcast_kernel<<<(T_TOK * HID) / (256 * 8), 256, 0, stream>>>(x, x_bf);
  router_kernel<<<T_TOK, 256, 0, stream>>>(x, gate_w, e_bias, ids, wts, counts);
  scan_kernel<<<1, 64, 0, stream>>>(counts, segoff, cursors, pair_e, pair_mt, npairs);
  scatter_kernel<<<(T_TOK * TOPK + 255) / 256, 256, 0, stream>>>(
      ids, wts, cursors, tok_list, wgt_list, pos_of);

  // routed gate (z=0) + up (z=1): A gathered via tok_list
  gemm_dma<0, true, true><<<dim3(IDIM / BN_, 128, 2), 256, 0, stream>>>(
      x_bf, w_gate, w_up, (long)IDIM * HID, HID, HID, g_buf, u_buf, IDIM,
      pair_e, pair_mt, npairs, segoff, counts, tok_list, 0);

  // h = silu(g)*u*w  (w includes ROUTED_SCALE and renorm)
  fuse_kernel<<<(T_TOK * TOPK * IDIM) / (256 * 8), 256, 0, stream>>>(g_buf, u_buf, wgt_list, 10);

  // shared gate (z=0) + up (z=1)
  gemm_dma<0, false, false><<<dim3(ISH / BN_, T_TOK / BM, 2), 256, 0, stream>>>(
      x_bf, sw_gu, sw_gu + (size_t)ISH * HID, 0, HID, HID, gs_buf, us_buf, ISH,
      nullptr, nullptr, nullptr, nullptr, nullptr, nullptr, T_TOK);
  fuse_kernel<<<(T_TOK * ISH) / (256 * 8), 256, 0, stream>>>(gs_buf, us_buf, nullptr, 11);

  // shared down: f32 stores into out (initializes all of d_out)
  gemm_dma<2, false, false><<<dim3(HID / BN_, T_TOK / BM, 1), 256, 0, stream>>>(
      gs_buf, sw_d, sw_d, 0, ISH, ISH, out, out, HID,
      nullptr, nullptr, nullptr, nullptr, nullptr, nullptr, T_TOK);

  // routed down -> y rows (bf16, atomic-free, segment-ordered; weight already in h)
  gemm_dma<0, true, false><<<dim3(HID / BN_, 128, 1), 256, 0, stream>>>(
      g_buf, w_down, w_down, (long)HID * IDIM, IDIM, IDIM, y_buf, y_buf, HID,
      pair_e, pair_mt, npairs, segoff, counts, tok_list, 0);

  // combine: out[t] += sum of this token's 8 y rows
  combine_kernel<<<T_TOK, 256, 0, stream>>>(y_buf, pos_of, out);
}

// Round 8
// 651.160 us; speedup vs baseline: 1.2034x; 1.0034x over previous
//
#include <hip/hip_runtime.h>
#include <hip/hip_bf16.h>
#include <math.h>

// Problem constants (match reference)
#define T_TOK 1024
#define HID   2048
#define NEXP  64
#define IDIM  1024
#define ISH   2048      // IS = I * N_SHARED
#define TOPK  8

typedef float  f32x4  __attribute__((ext_vector_type(4)));
typedef __bf16 bf16x8 __attribute__((ext_vector_type(8)));

#define BM  128
#define BN_ 64

__device__ __forceinline__ bf16x8 cvt8(f32x4 a, f32x4 b) {
  bf16x8 v;
  v[0]=(__bf16)a[0]; v[1]=(__bf16)a[1]; v[2]=(__bf16)a[2]; v[3]=(__bf16)a[3];
  v[4]=(__bf16)b[0]; v[5]=(__bf16)b[1]; v[6]=(__bf16)b[2]; v[7]=(__bf16)b[3];
  return v;
}

// ---------------- init: zero expert counts ----------------
__global__ void init_kernel(int* counts) {
  if (threadIdx.x < NEXP) counts[threadIdx.x] = 0;
}

// ---------------- x (f32) -> x_bf16 ----------------
__global__ void xcast_kernel(const float* __restrict__ x, __bf16* __restrict__ xb) {
  long i = ((long)blockIdx.x * 256 + threadIdx.x) * 8;
  f32x4 a = *(const f32x4*)(x + i);
  f32x4 b = *(const f32x4*)(x + i + 4);
  *(bf16x8*)(xb + i) = cvt8(a, b);
}

// ---------------- router: logits + sigmoid + grouped top-k (f32) ----------------
__global__ __launch_bounds__(256)
void router_kernel(const float* __restrict__ x, const float* __restrict__ gw,
                   const float* __restrict__ eb,
                   int* __restrict__ ids, float* __restrict__ wts,
                   int* __restrict__ counts)
{
  __shared__ __align__(16) float xs[HID];
  __shared__ float red[256];
  __shared__ float sc[NEXP], sb[NEXP];
  const int t = blockIdx.x, tid = threadIdx.x;

  const f32x4* xsrc = (const f32x4*)(x + (long)t * HID);
  f32x4* xd = (f32x4*)xs;
  xd[tid]       = xsrc[tid];
  xd[tid + 256] = xsrc[tid + 256];
  __syncthreads();

  const int e = tid & 63, part = tid >> 6;
  const f32x4* wrow = (const f32x4*)(gw + (long)e * HID + part * 512);
  const f32x4* xrow = (const f32x4*)(xs + part * 512);
  float s = 0.f;
  #pragma unroll 4
  for (int j = 0; j < 128; ++j) {
    f32x4 wv = wrow[j], xv = xrow[j];
    s += wv[0]*xv[0] + wv[1]*xv[1] + wv[2]*xv[2] + wv[3]*xv[3];
  }
  red[tid] = s;
  __syncthreads();
  if (part == 0) {
    float logit = red[e] + red[e+64] + red[e+128] + red[e+192];
    float sig = 1.f / (1.f + expf(-logit));   // accurate exp: selection must match f32 ref
    sc[e] = sig; sb[e] = sig + eb[e];
  }
  __syncthreads();

  if (tid == 0) {
    float gsc[8];
    for (int g = 0; g < 8; ++g) {
      float m1 = -1e30f, m2 = -1e30f;
      for (int j = 0; j < 8; ++j) {
        float v = sb[g*8 + j];
        if (v > m1) { m2 = m1; m1 = v; } else if (v > m2) m2 = v;
      }
      gsc[g] = m1 + m2;
    }
    unsigned gmask = 0;
    for (int it = 0; it < 4; ++it) {
      int best = 0; float bv = -1e30f;
      for (int g = 0; g < 8; ++g)
        if (!((gmask >> g) & 1) && gsc[g] > bv) { bv = gsc[g]; best = g; }
      gmask |= 1u << best;
    }
    unsigned long long taken = 0;
    int id8[8]; float wsum = 0.f;
    for (int it = 0; it < 8; ++it) {
      int best = 0; float bv = -1e30f;
      for (int e2 = 0; e2 < 64; ++e2) {
        if (!((gmask >> (e2 >> 3)) & 1)) continue;
        if ((taken >> e2) & 1) continue;
        float v = sb[e2];
        if (v > bv) { bv = v; best = e2; }
      }
      taken |= 1ull << best;
      id8[it] = best; wsum += sc[best];
    }
    float inv = 2.5f / wsum;   // fold ROUTED_SCALE into weights
    for (int k = 0; k < 8; ++k) {
      ids[t*8 + k] = id8[k];
      wts[t*8 + k] = sc[id8[k]] * inv;
      atomicAdd(&counts[id8[k]], 1);
    }
  }
}

// ---------------- prefix scan + (expert, mt) pair worklist (BM=128 chunks) ----
__global__ void scan_kernel(const int* __restrict__ counts,
                            int* __restrict__ seg_off, int* __restrict__ cursors,
                            int* __restrict__ pair_e, int* __restrict__ pair_mt,
                            int* __restrict__ npairs) {
  if (threadIdx.x == 0) {
    int off = 0, np = 0;
    for (int e = 0; e < NEXP; ++e) {
      seg_off[e] = off; cursors[e] = off;
      int c = counts[e]; off += c;
      for (int m = 0; m * BM < c; ++m) { pair_e[np] = e; pair_mt[np] = m; ++np; }
    }
    npairs[0] = np;
  }
}

// ---------------- scatter (t, w) into per-expert segments ----------------
__global__ void scatter_kernel(const int* __restrict__ ids, const float* __restrict__ wts,
                               int* __restrict__ cursors,
                               int* __restrict__ tok_list, float* __restrict__ wgt_list,
                               int* __restrict__ pos_of) {
  int idx = blockIdx.x * 256 + threadIdx.x;
  if (idx >= T_TOK * TOPK) return;
  int t = idx >> 3;
  int e = ids[idx];
  int pos = atomicAdd(&cursors[e], 1);
  tok_list[pos] = t;
  wgt_list[pos] = wts[idx];
  pos_of[idx] = pos;
}

// ---------------- wave-autonomous K-split streaming GEMM ----------------
// Tile M=128 x N=64. 4 waves split K: wave w handles k-chunks (4s+w)*32.
// Each wave DMA-stages its PRIVATE A-slice (8KB bf16) + B-slice (8KB f32)
// into a private 2x16KB LDS double buffer via global_load_lds, loops
// {STAGE(s+1); vmcnt(16); COMPUTE(s)} with NO barrier -> 4 independent
// DMA streams per CU, outstanding bytes never collectively drain.
// Full 128x64 f32 accumulator per wave (128 VGPR); cross-wave LDS reduce
// + store at the end. EPI 0: bf16 C store. EPI 2: f32 store.
template<int EPI, bool ROUTED, bool GATHER>
__global__ __launch_bounds__(256, 1)
void gemm_ks(const __bf16* __restrict__ A, const float* __restrict__ Bg0,
             const float* __restrict__ Bu0, long strideBe, int ldB, int K,
             void* Cg, void* Cu, int ldc,
             const int* __restrict__ pair_e, const int* __restrict__ pair_mt,
             const int* __restrict__ npairs,
             const int* __restrict__ seg_off, const int* __restrict__ seg_cnt,
             const int* __restrict__ tok_list, int Mfull)
{
  __shared__ __align__(16) char smem[4 * 32768];   // 128 KB: 32 KB per wave
  const int tid = threadIdx.x, lane = tid & 63, wv = tid >> 6;
  const int c15 = lane & 15, hi = lane >> 4;

  int e, mt0, soff, cnt;
  if (ROUTED) {
    int p = blockIdx.y;
    if (p >= npairs[0]) return;
    e = pair_e[p]; mt0 = pair_mt[p]; soff = seg_off[e]; cnt = seg_cnt[e];
  } else {
    e = 0; mt0 = blockIdx.y; soff = 0; cnt = Mfull;
  }
  const int rem = cnt - mt0 * BM;
  if (rem <= 0) return;

  const float* B0 = (gridDim.z == 2 && blockIdx.z) ? Bu0 : Bg0;
  void* Cout      = (gridDim.z == 2 && blockIdx.z) ? Cu  : Cg;
  const float* Bb0 = B0 + (long)e * strideBe;

  char* Wb = smem + wv * 32768;   // this wave's private 32 KB

  // staging sources (include wave k-base wv*32; advance by s*128 elems/step)
  const __bf16* srcA[8];
  const float*  srcB[8];
  #pragma unroll
  for (int i = 0; i < 8; ++i) {
    int row = i * 16 + (lane >> 2);
    int kcA = (lane & 3) ^ (row & 3);
    int rr  = (row < rem) ? row : (rem - 1);
    int idx = soff + mt0 * BM + rr;
    long arow = GATHER ? (long)tok_list[idx] : (long)idx;
    srcA[i] = A + arow * (long)K + wv * 32 + kcA * 8;

    int col = i * 8 + (lane >> 3);
    int kcB = (lane & 7) ^ (col & 7);
    srcB[i] = Bb0 + (long)(blockIdx.x * BN_ + col) * ldB + wv * 32 + kcB * 4;
  }

#define STAGE(b, kk) { \
  char* Ad = Wb + (b) * 16384; \
  char* Bd = Ad + 8192; \
  _Pragma("unroll") \
  for (int i = 0; i < 8; ++i) \
    __builtin_amdgcn_global_load_lds((const __attribute__((address_space(1))) void*)(srcA[i] + (kk)), \
        (__attribute__((address_space(3))) void*)(Ad + i * 1024), 16, 0, 0); \
  _Pragma("unroll") \
  for (int i = 0; i < 8; ++i) \
    __builtin_amdgcn_global_load_lds((const __attribute__((address_space(1))) void*)(srcB[i] + (kk)), \
        (__attribute__((address_space(3))) void*)(Bd + i * 1024), 16, 0, 0); }

  f32x4 acc[8][4] = {};

#define COMPUTE(b) { \
  const char* Al = Wb + (b) * 16384; \
  const char* Bl = Al + 8192; \
  bf16x8 bfrag[4]; \
  _Pragma("unroll") \
  for (int n = 0; n < 4; ++n) { \
    int col = n * 16 + c15; \
    f32x4 b0 = *(const f32x4*)(Bl + col * 128 + (((hi * 2    ) ^ (col & 7)) << 4)); \
    f32x4 b1 = *(const f32x4*)(Bl + col * 128 + (((hi * 2 + 1) ^ (col & 7)) << 4)); \
    bfrag[n] = cvt8(b0, b1); \
  } \
  _Pragma("unroll") \
  for (int m = 0; m < 8; ++m) { \
    int row = m * 16 + c15; \
    bf16x8 af = *(const bf16x8*)(Al + row * 64 + ((hi ^ (row & 3)) << 4)); \
    _Pragma("unroll") \
    for (int n = 0; n < 4; ++n) \
      acc[m][n] = __builtin_amdgcn_mfma_f32_16x16x32_bf16(af, bfrag[n], acc[m][n], 0, 0, 0); \
  } }

  const int S = K / 128;           // own-steps per wave (16 or 8)
  STAGE(0, 0);
  for (int s = 0; s < S; ++s) {
    if (s + 1 < S) {
      STAGE((s + 1) & 1, (s + 1) * 128);
      asm volatile("s_waitcnt vmcnt(16)" ::: "memory");  // stage(s) landed; s+1 in flight
    } else {
      asm volatile("s_waitcnt vmcnt(0)" ::: "memory");
    }
    COMPUTE(s & 1);
  }
#undef STAGE
#undef COMPUTE

  // ---- cross-wave reduction: each wave writes its 128x64 f32 partial ----
  float* Pw = (float*)Wb;
  #pragma unroll
  for (int m = 0; m < 8; ++m)
    #pragma unroll
    for (int n = 0; n < 4; ++n)
      #pragma unroll
      for (int r = 0; r < 4; ++r)
        Pw[(m * 16 + hi * 4 + r) * 64 + n * 16 + c15] = acc[m][n][r];
  __syncthreads();

  const f32x4* P0 = (const f32x4*)(smem);
  const f32x4* P1 = (const f32x4*)(smem + 32768);
  const f32x4* P2 = (const f32x4*)(smem + 65536);
  const f32x4* P3 = (const f32x4*)(smem + 98304);
  #pragma unroll
  for (int j = 0; j < 4; ++j) {
    int a = j * 2048 + tid * 8;            // f32 index into 128x64 tile
    int q = a >> 2;
    f32x4 v0 = P0[q]     + P1[q]     + P2[q]     + P3[q];
    f32x4 v1 = P0[q + 1] + P1[q + 1] + P2[q + 1] + P3[q + 1];
    int row = a >> 6, col = a & 63;
    if (row < rem) {
      if (EPI == 0) {
        __bf16* Cb = (__bf16*)Cout;
        *(bf16x8*)(Cb + (long)(soff + mt0 * BM + row) * ldc + blockIdx.x * BN_ + col) = cvt8(v0, v1);
      } else {
        float* O = (float*)Cout;
        float* dst = O + (long)(mt0 * BM + row) * ldc + blockIdx.x * BN_ + col;
        *(f32x4*)dst = v0;
        *(f32x4*)(dst + 4) = v1;
      }
    }
  }
}

// ---------------- fuse: h = silu(g) * u * w  (in place into g) ----------------
__global__ void fuse_kernel(__bf16* __restrict__ g, const __bf16* __restrict__ u,
                            const float* __restrict__ wrow, int rshift) {
  long idx = ((long)blockIdx.x * 256 + threadIdx.x) * 8;
  bf16x8 gv = *(bf16x8*)(g + idx);
  bf16x8 uv = *(const bf16x8*)(u + idx);
  float w = wrow ? wrow[idx >> rshift] : 1.f;
  bf16x8 h;
  #pragma unroll
  for (int j = 0; j < 8; ++j) {
    float gf = (float)gv[j], uf = (float)uv[j];
    h[j] = (__bf16)(w * gf * uf / (1.f + __expf(-gf)));
  }
  *(bf16x8*)(g + idx) = h;
}

// ---------------- combine: out[t] += sum_k y[pos(t,k)] ----------------
__global__ __launch_bounds__(256)
void combine_kernel(const __bf16* __restrict__ y, const int* __restrict__ pos_of,
                    float* __restrict__ out) {
  const int t = blockIdx.x;
  const int c0 = threadIdx.x * 8;
  float* orow = out + (long)t * HID + c0;
  f32x4 s0 = *(const f32x4*)orow;
  f32x4 s1 = *(const f32x4*)(orow + 4);
  #pragma unroll
  for (int k = 0; k < TOPK; ++k) {
    int row = pos_of[t * TOPK + k];
    bf16x8 v = *(const bf16x8*)(y + (long)row * HID + c0);
    s0[0] += (float)v[0]; s0[1] += (float)v[1]; s0[2] += (float)v[2]; s0[3] += (float)v[3];
    s1[0] += (float)v[4]; s1[1] += (float)v[5]; s1[2] += (float)v[6]; s1[3] += (float)v[7];
  }
  *(f32x4*)orow = s0;
  *(f32x4*)(orow + 4) = s1;
}

// ---------------- launch ----------------
extern "C" void kernel_launch(void* const* d_in, const int* in_sizes, int n_in,
                              void* d_out, int out_size, void* d_ws, size_t ws_size,
                              hipStream_t stream) {
  const float* x      = (const float*)d_in[0];
  const float* gate_w = (const float*)d_in[1];
  const float* e_bias = (const float*)d_in[2];
  const float* w_gate = (const float*)d_in[3];
  const float* w_up   = (const float*)d_in[4];
  const float* w_down = (const float*)d_in[5];
  const float* sw_gu  = (const float*)d_in[6];
  const float* sw_d   = (const float*)d_in[7];
  float* out = (float*)d_out;
  char* ws = (char*)d_ws;

  size_t off = 0;
  __bf16* x_bf = (__bf16*)(ws + off);        off += (size_t)T_TOK * HID * 2;   // 4 MB
  int*    ids  = (int*)(ws + off);           off += T_TOK * TOPK * 4;
  float*  wts  = (float*)(ws + off);         off += T_TOK * TOPK * 4;
  int* counts  = (int*)(ws + off);           off += 256;
  int* segoff  = (int*)(ws + off);           off += 256;
  int* cursors = (int*)(ws + off);           off += 256;
  int* pair_e  = (int*)(ws + off);           off += 1024;
  int* pair_mt = (int*)(ws + off);           off += 1024;
  int* npairs  = (int*)(ws + off);           off += 256;
  int* tok_list = (int*)(ws + off);          off += T_TOK * TOPK * 4;
  float* wgt_list = (float*)(ws + off);      off += T_TOK * TOPK * 4;
  int* pos_of  = (int*)(ws + off);           off += T_TOK * TOPK * 4;
  off = (off + 255) & ~(size_t)255;
  __bf16* g_buf  = (__bf16*)(ws + off);      off += (size_t)T_TOK * TOPK * IDIM * 2; // 16 MB
  __bf16* u_buf  = (__bf16*)(ws + off);      off += (size_t)T_TOK * TOPK * IDIM * 2; // 16 MB
  __bf16* gs_buf = (__bf16*)(ws + off);      off += (size_t)T_TOK * ISH * 2;         // 4 MB
  __bf16* us_buf = (__bf16*)(ws + off);      off += (size_t)T_TOK * ISH * 2;         // 4 MB
  __bf16* y_buf  = (__bf16*)(ws + off);      off += (size_t)T_TOK * TOPK * HID * 2;  // 32 MB

  init_kernel<<<1, 64, 0, stream>>>(counts);
  xcast_kernel<<<(T_TOK * HID) / (256 * 8), 256, 0, stream>>>(x, x_bf);
  router_kernel<<<T_TOK, 256, 0, stream>>>(x, gate_w, e_bias, ids, wts, counts);
  scan_kernel<<<1, 64, 0, stream>>>(counts, segoff, cursors, pair_e, pair_mt, npairs);
  scatter_kernel<<<(T_TOK * TOPK + 255) / 256, 256, 0, stream>>>(
      ids, wts, cursors, tok_list, wgt_list, pos_of);

  // routed gate (z=0) + up (z=1): A gathered via tok_list
  gemm_ks<0, true, true><<<dim3(IDIM / BN_, 128, 2), 256, 0, stream>>>(
      x_bf, w_gate, w_up, (long)IDIM * HID, HID, HID, g_buf, u_buf, IDIM,
      pair_e, pair_mt, npairs, segoff, counts, tok_list, 0);

  // h = silu(g)*u*w  (w includes ROUTED_SCALE and renorm)
  fuse_kernel<<<(T_TOK * TOPK * IDIM) / (256 * 8), 256, 0, stream>>>(g_buf, u_buf, wgt_list, 10);

  // shared gate (z=0) + up (z=1)
  gemm_ks<0, false, false><<<dim3(ISH / BN_, T_TOK / BM, 2), 256, 0, stream>>>(
      x_bf, sw_gu, sw_gu + (size_t)ISH * HID, 0, HID, HID, gs_buf, us_buf, ISH,
      nullptr, nullptr, nullptr, nullptr, nullptr, nullptr, T_TOK);
  fuse_kernel<<<(T_TOK * ISH) / (256 * 8), 256, 0, stream>>>(gs_buf, us_buf, nullptr, 11);

  // shared down: f32 stores into out (initializes all of d_out)
  gemm_ks<2, false, false><<<dim3(HID / BN_, T_TOK / BM, 1), 256, 0, stream>>>(
      gs_buf, sw_d, sw_d, 0, ISH, ISH, out, out, HID,
      nullptr, nullptr, nullptr, nullptr, nullptr, nullptr, T_TOK);

  // routed down -> y rows (bf16, atomic-free, segment-ordered; weight already in h)
  gemm_ks<0, true, false><<<dim3(HID / BN_, 128, 1), 256, 0, stream>>>(
      g_buf, w_down, w_down, (long)HID * IDIM, IDIM, IDIM, y_buf, y_buf, HID,
      pair_e, pair_mt, npairs, segoff, counts, tok_list, 0);

  // combine: out[t] += sum of this token's 8 y rows
  combine_kernel<<<T_TOK, 256, 0, stream>>>(y_buf, pos_of, out);
}